// Round 13
// baseline (249.797 us; speedup 1.0000x reference)
//
#include <hip/hip_runtime.h>
#include <stdint.h>

#define NN 10000
#define DIMV 256
#define HID 512
#define NEDGE 320000
#define SPLIT 6
#define KCH 1664      // k per chunk (52 tiles); chunk 5: 53 tiles incl. zero-pad tile 312
#define NKT 313
#define APL 2112      // A LDS plane stride bytes (128*16 + 64 pad)
#define ABUF 8448     // 4*APL
#define LDSZ 16896    // 2*ABUF (A double buffer only; B reads straight from L2)

typedef __attribute__((ext_vector_type(8))) short bf16x8;
typedef __attribute__((ext_vector_type(4))) float f32x4;
typedef __attribute__((ext_vector_type(4))) unsigned short u16x4;
typedef __attribute__((ext_vector_type(2))) unsigned int u32x2;

__device__ __forceinline__ unsigned short f2bf(float f) {
  union { float f; unsigned int u; } c; c.f = f;
  return (unsigned short)((c.u + 0x7FFFu + ((c.u >> 16) & 1u)) >> 16);
}
__device__ __forceinline__ float bf2f(unsigned short h) {
  union { unsigned int u; float f; } c; c.u = ((unsigned int)h) << 16;
  return c.f;
}

__device__ __forceinline__ bf16x8 bzero8() {
  bf16x8 r;
#pragma unroll
  for (int i = 0; i < 8; ++i) r[i] = 0;
  return r;
}

__device__ __forceinline__ bf16x8 pack8(const float* x) {
  bf16x8 r;
#pragma unroll
  for (int i = 0; i < 8; ++i) r[i] = (short)f2bf(x[i]);
  return r;
}

// f32x4 -> 4 packed bf16 (8B) via v_cvt_pk_bf16_f32 (RNE, matches f2bf)
__device__ __forceinline__ u32x2 cvt4v(const f32x4 a) {
  u32x2 r;
  asm("v_cvt_pk_bf16_f32 %0, %1, %2" : "=v"(r[0]) : "v"(a[0]), "v"(a[1]));
  asm("v_cvt_pk_bf16_f32 %0, %1, %2" : "=v"(r[1]) : "v"(a[2]), "v"(a[3]));
  return r;
}

// ---------------------------------------------------------------------------
// K0: weights fp32 -> bf16, FRAGMENT-READY [ktile][col][32k] layout (vB-style);
//     zero vB k-pad (tile 312, kk 16..31); zero counts
// ---------------------------------------------------------------------------
__global__ void k_conv(const float* __restrict__ W1, const float* __restrict__ W2,
                       const float* __restrict__ Wl1, const float* __restrict__ Wl2,
                       unsigned short* __restrict__ W1T, unsigned short* __restrict__ W2T,
                       unsigned short* __restrict__ Wl1T, unsigned short* __restrict__ Wl2T,
                       unsigned short* __restrict__ vB, int* __restrict__ counts) {
  int i = blockIdx.x * 256 + threadIdx.x;
  if (i < 131072) {
    {  // W1T fragment-ready: 8 tiles x [512 o][32 kk]; W1 is [256 k][512 o]
      int tile = i >> 14, o = (i >> 5) & 511, kk = i & 31;
      W1T[i] = f2bf(W1[(size_t)(tile * 32 + kk) * 512 + o]);
    }
    {  // W2T fragment-ready: 16 tiles x [256 o][32 kk]; W2 is [512 k][256 o]
      int tile = i >> 13, o = (i >> 5) & 255, kk = i & 31;
      W2T[i] = f2bf(W2[(size_t)(tile * 32 + kk) * 256 + o]);
    }
    if (i < 65536) {  // Wl1/Wl2 fragment-ready: 8 tiles x [256 o][32 kk]
      int tile = i >> 13, o = (i >> 5) & 255, kk = i & 31;
      int srci = (tile * 32 + kk) * 256 + o;
      Wl1T[i] = f2bf(Wl1[srci]);
      Wl2T[i] = f2bf(Wl2[srci]);
    }
    if (i < 4096) {  // zero vB tile 312, kk in [16,32), swizzled address
      int c = i >> 4, kk = 16 + (i & 15);
      int g = kk >> 3;
      int byte = c * 64 + ((g ^ ((c >> 1) & 3)) << 4) + (kk & 7) * 2;
      *(unsigned short*)((char*)vB + (size_t)312 * 16384 + byte) = 0;
    }
    if (i < NN) counts[i] = 0;
  }
}

// ---------------------------------------------------------------------------
// K1: blocks 0..312: v = relu(vc + relu(vc@W1+b1)@W2 + b2) -> v_rm, vB
//     blocks 313..352: dst histogram.  B-operands straight from L2.
// ---------------------------------------------------------------------------
__launch_bounds__(256, 2)
__global__ void k_mlp(const float* __restrict__ vc,
                      const unsigned short* __restrict__ W1T, const float* __restrict__ b1,
                      const unsigned short* __restrict__ W2T, const float* __restrict__ b2,
                      unsigned short* __restrict__ v_rm, unsigned short* __restrict__ vB,
                      const int* __restrict__ dst, int* __restrict__ counts) {
  if (blockIdx.x >= 313) {  // fused histogram
    const int e0 = (blockIdx.x - 313) * 256 + threadIdx.x;
    for (int e = e0; e < NEDGE; e += 40 * 256) atomicAdd(&counts[dst[e]], 1);
    return;
  }
  __shared__ __align__(16) char sm[49152];
  const int t = threadIdx.x;
  const int lane = t & 63, wid = t >> 6;
  const int wr = wid & 1, wc = wid >> 1;
  const int r0 = blockIdx.x * 32;

  {  // stage vc tile -> bf16 (region 0..16K)
    const int row = t >> 3, grow = r0 + row;
#pragma unroll
    for (int q = 0; q < 4; ++q) {
      const int slot = (t & 7) * 4 + q;
      float buf[8] = {0.f, 0.f, 0.f, 0.f, 0.f, 0.f, 0.f, 0.f};
      if (grow < NN) {
        const float4 x0 = *(const float4*)(vc + (size_t)grow * DIMV + slot * 8);
        const float4 x1 = *(const float4*)(vc + (size_t)grow * DIMV + slot * 8 + 4);
        buf[0] = x0.x; buf[1] = x0.y; buf[2] = x0.z; buf[3] = x0.w;
        buf[4] = x1.x; buf[5] = x1.y; buf[6] = x1.z; buf[7] = x1.w;
      }
      *(bf16x8*)(sm + row * 512 + ((slot ^ (row & 7)) * 16)) = pack8(buf);
    }
  }
  __syncthreads();  // barrier #1: vcb ready

  f32x4 acc1[16];
#pragma unroll
  for (int i = 0; i < 16; ++i) acc1[i] = (f32x4){0.f, 0.f, 0.f, 0.f};

#pragma unroll 1
  for (int step = 0; step < 8; ++step) {
    const int arow = 16 * wr + (lane & 15);
    const int aslot = step * 4 + (lane >> 4);
    const bf16x8 af = *(const bf16x8*)(sm + arow * 512 + ((aslot ^ (arow & 7)) * 16));
    const unsigned short* wb = W1T + step * 16384 + (lane & 15) * 32 + (lane >> 4) * 8;
#pragma unroll
    for (int ct = 0; ct < 16; ++ct) {
      const int c0 = 256 * wc + 16 * ct;
      const bf16x8 bfr = *(const bf16x8*)(wb + c0 * 32);
      acc1[ct] = __builtin_amdgcn_mfma_f32_16x16x32_bf16(af, bfr, acc1[ct], 0, 0, 0);
    }
  }

  // h = relu(acc1 + b1) -> bf16 LDS [32][512] at 16384 (vcb dead)
#pragma unroll
  for (int ct = 0; ct < 16; ++ct) {
    const int c = 256 * wc + 16 * ct + (lane & 15);
    const float bb = b1[c];
#pragma unroll
    for (int r = 0; r < 4; ++r) {
      const int row = 16 * wr + (lane >> 4) * 4 + r;
      float v = fmaxf(acc1[ct][r] + bb, 0.f);
      const int slot = c >> 3;
      *(unsigned short*)(sm + 16384 + row * 1024 + ((slot ^ (row & 7)) * 16) + (c & 7) * 2) =
          f2bf(v);
    }
  }
  __syncthreads();  // barrier #2: h ready

  f32x4 acc2[8];
#pragma unroll
  for (int i = 0; i < 8; ++i) acc2[i] = (f32x4){0.f, 0.f, 0.f, 0.f};

#pragma unroll 1
  for (int step = 0; step < 16; ++step) {
    const int arow = 16 * wr + (lane & 15);
    const int aslot = step * 4 + (lane >> 4);
    const bf16x8 af = *(const bf16x8*)(sm + 16384 + arow * 1024 + ((aslot ^ (arow & 7)) * 16));
    const unsigned short* wb = W2T + step * 8192 + (lane & 15) * 32 + (lane >> 4) * 8;
#pragma unroll
    for (int ct = 0; ct < 8; ++ct) {
      const int c0 = 128 * wc + 16 * ct;
      const bf16x8 bfr = *(const bf16x8*)(wb + c0 * 32);
      acc2[ct] = __builtin_amdgcn_mfma_f32_16x16x32_bf16(af, bfr, acc2[ct], 0, 0, 0);
    }
  }

  const int growbase = r0 + 16 * wr + (lane >> 4) * 4;
  if (growbase < NN) {
#pragma unroll
    for (int ct = 0; ct < 8; ++ct) {
      const int c = 128 * wc + 16 * ct + (lane & 15);
      const float bb = b2[c];
      u16x4 pk;
#pragma unroll
      for (int r = 0; r < 4; ++r) {
        const int grow = growbase + r;
        float v = acc2[ct][r] + bb + vc[(size_t)grow * DIMV + c];
        v = fmaxf(v, 0.f);
        const unsigned short hv = f2bf(v);
        v_rm[(size_t)grow * DIMV + c] = hv;
        pk[r] = hv;
      }
      const int tile = growbase >> 5, kk0 = growbase & 31;
      const int g = kk0 >> 3;
      const int byte = c * 64 + ((g ^ ((c >> 1) & 3)) << 4) + (kk0 & 7) * 2;
      *(u16x4*)((char*)vB + (size_t)tile * 16384 + byte) = pk;
    }
  }
}

// ---------------------------------------------------------------------------
// K2: blocks 0..473: Av = A @ v. BM=128, BN=256, BK=32, 512 thr (2 wr x 4 wc).
// A: HBM->regs->cvt->bf16 LDS dbuf (R8-proven, 1 barrier/step).
// B: fragment-ready vB read STRAIGHT FROM L2 to VGPRs (dense 1KB/wave loads,
// XCD-local slice) — no B LDS traffic at all. block 474: fused scan.
// ---------------------------------------------------------------------------
__launch_bounds__(512, 4)
__global__ void k_av(const float* __restrict__ A, const unsigned short* __restrict__ vB,
                     unsigned short* __restrict__ avpb,
                     const int* __restrict__ counts, int* __restrict__ offsets,
                     int* __restrict__ cursor) {
  __shared__ __align__(16) char sm[LDSZ];
  const int t = threadIdx.x, lane = t & 63, wid = t >> 6;

  if (blockIdx.x >= 474) {  // fused exclusive scan (512 threads, 8 waves)
    int* wred = (int*)sm;
    int carry = 0;
    for (int base = 0; base < NN; base += 512) {
      const int i = base + t;
      const int x = (i < NN) ? counts[i] : 0;
      int v = x;
#pragma unroll
      for (int d = 1; d < 64; d <<= 1) {
        int y = __shfl_up(v, d);
        if (lane >= d) v += y;
      }
      if (lane == 63) wred[wid] = v;
      __syncthreads();
      if (t < 8) {
        int sv = wred[t];
#pragma unroll
        for (int d = 1; d < 8; d <<= 1) {
          int y = __shfl_up(sv, d);
          if (t >= d) sv += y;
        }
        wred[t] = sv;
      }
      __syncthreads();
      const int excl = carry + (wid ? wred[wid - 1] : 0) + v - x;
      if (i < NN) { offsets[i] = excl; cursor[i] = excl; }
      carry += wred[7];
      __syncthreads();
    }
    if (t == 0) offsets[NN] = carry;
    return;
  }

  const int wr = wid >> 2, wc = wid & 3;

  // bijective XCD-chunked remap of 474 blocks
  const int orig = blockIdx.x;
  const int xcd = orig & 7, idx = orig >> 3;
  const int g = (xcd < 2) ? xcd * 60 + idx : 120 + (xcd - 2) * 59 + idx;
  const int s = g / 79;          // k-chunk 0..5
  const int xb = g - s * 79;     // row-block 0..78
  const int r0 = xb * 128;
  const int kbase = s * KCH;
  const int tile0 = s * 52;
  const int nst = (s == SPLIT - 1) ? 53 : 52;
  unsigned short* outp = avpb + (size_t)s * NN * DIMV;

  const int srow = t >> 3, sQ = t & 7;
  const float* ap0 = A + (size_t)min(r0 + srow, NN - 1) * NN;
  const float* ap1 = A + (size_t)min(r0 + 64 + srow, NN - 1) * NN;
  const int wbase = (sQ >> 1) * APL + (sQ & 1) * 8;
  const int w0 = wbase + srow * 16;
  const int w1 = wbase + (64 + srow) * 16;

  f32x4 aR0, aR1;

#define AISSUE(ST)                                            \
  do {                                                        \
    int kq = min(kbase + (ST)*32 + sQ * 4, 9996);             \
    aR0 = *(const f32x4*)(ap0 + kq);                          \
    aR1 = *(const f32x4*)(ap1 + kq);                          \
  } while (0)

#define AWRITE(BUF)                                           \
  do {                                                        \
    char* wb = sm + (BUF)*ABUF;                               \
    *(u32x2*)(wb + w0) = cvt4v(aR0);                          \
    *(u32x2*)(wb + w1) = cvt4v(aR1);                          \
  } while (0)

  f32x4 acc[4][4];
#pragma unroll
  for (int i = 0; i < 4; ++i)
#pragma unroll
    for (int j = 0; j < 4; ++j) acc[i][j] = (f32x4){0.f, 0.f, 0.f, 0.f};

  const int rbase = (lane >> 4) * APL + (wr * 64 + (lane & 15)) * 16;
  int boff[4];  // byte offsets into a vB tile (dense 1KB coalesced per wave)
#pragma unroll
  for (int ct = 0; ct < 4; ++ct) {
    const int col = wc * 64 + ct * 16 + (lane & 15);
    boff[ct] = col * 64 + (((lane >> 4) ^ ((col >> 1) & 3)) << 4);
  }

#define COMPUTE(CUR, ST)                                                           \
  do {                                                                            \
    const char* ab = sm + (CUR)*ABUF;                                             \
    const char* bt = (const char*)vB + (size_t)(tile0 + (ST)) * 16384;            \
    const bf16x8 bf0 = *(const bf16x8*)(bt + boff[0]);                            \
    const bf16x8 bf1 = *(const bf16x8*)(bt + boff[1]);                            \
    const bf16x8 bf2 = *(const bf16x8*)(bt + boff[2]);                            \
    const bf16x8 bf3 = *(const bf16x8*)(bt + boff[3]);                            \
    const bf16x8 af0 = *(const bf16x8*)(ab + rbase);                              \
    const bf16x8 af1 = *(const bf16x8*)(ab + rbase + 256);                        \
    const bf16x8 af2 = *(const bf16x8*)(ab + rbase + 512);                        \
    const bf16x8 af3 = *(const bf16x8*)(ab + rbase + 768);                        \
    acc[0][0] = __builtin_amdgcn_mfma_f32_16x16x32_bf16(af0, bf0, acc[0][0], 0, 0, 0); \
    acc[1][0] = __builtin_amdgcn_mfma_f32_16x16x32_bf16(af1, bf0, acc[1][0], 0, 0, 0); \
    acc[2][0] = __builtin_amdgcn_mfma_f32_16x16x32_bf16(af2, bf0, acc[2][0], 0, 0, 0); \
    acc[3][0] = __builtin_amdgcn_mfma_f32_16x16x32_bf16(af3, bf0, acc[3][0], 0, 0, 0); \
    acc[0][1] = __builtin_amdgcn_mfma_f32_16x16x32_bf16(af0, bf1, acc[0][1], 0, 0, 0); \
    acc[1][1] = __builtin_amdgcn_mfma_f32_16x16x32_bf16(af1, bf1, acc[1][1], 0, 0, 0); \
    acc[2][1] = __builtin_amdgcn_mfma_f32_16x16x32_bf16(af2, bf1, acc[2][1], 0, 0, 0); \
    acc[3][1] = __builtin_amdgcn_mfma_f32_16x16x32_bf16(af3, bf1, acc[3][1], 0, 0, 0); \
    acc[0][2] = __builtin_amdgcn_mfma_f32_16x16x32_bf16(af0, bf2, acc[0][2], 0, 0, 0); \
    acc[1][2] = __builtin_amdgcn_mfma_f32_16x16x32_bf16(af1, bf2, acc[1][2], 0, 0, 0); \
    acc[2][2] = __builtin_amdgcn_mfma_f32_16x16x32_bf16(af2, bf2, acc[2][2], 0, 0, 0); \
    acc[3][2] = __builtin_amdgcn_mfma_f32_16x16x32_bf16(af3, bf2, acc[3][2], 0, 0, 0); \
    acc[0][3] = __builtin_amdgcn_mfma_f32_16x16x32_bf16(af0, bf3, acc[0][3], 0, 0, 0); \
    acc[1][3] = __builtin_amdgcn_mfma_f32_16x16x32_bf16(af1, bf3, acc[1][3], 0, 0, 0); \
    acc[2][3] = __builtin_amdgcn_mfma_f32_16x16x32_bf16(af2, bf3, acc[2][3], 0, 0, 0); \
    acc[3][3] = __builtin_amdgcn_mfma_f32_16x16x32_bf16(af3, bf3, acc[3][3], 0, 0, 0); \
  } while (0)

  // prologue
  AISSUE(0);
  AWRITE(0);
  __syncthreads();

  int cur = 0;
  for (int st = 0; st < nst; ++st) {
    const bool more = (st + 1 < nst);
    if (more) AISSUE(st + 1);          // A HBM loads (long pole) issue first
    COMPUTE(cur, st);                  // B from L2 + A from LDS -> MFMAs
    if (more) AWRITE(cur ^ 1);         // cvt+ds_write after MFMA cluster
    __syncthreads();
    cur ^= 1;
  }
#undef AISSUE
#undef AWRITE
#undef COMPUTE

  // epilogue: bf16 partials
#pragma unroll
  for (int rt = 0; rt < 4; ++rt) {
    const int gb = r0 + wr * 64 + rt * 16 + (lane >> 4) * 4;
    if (gb < NN) {
#pragma unroll
      for (int ct = 0; ct < 4; ++ct) {
        const int col = wc * 64 + ct * 16 + (lane & 15);
#pragma unroll
        for (int r = 0; r < 4; ++r)
          outp[(size_t)(gb + r) * DIMV + col] = f2bf(acc[rt][ct][r]);
      }
    }
  }
}

// ---------------------------------------------------------------------------
// K3: blocks 0..312: v2 = relu(v@Wl1+bl1) + relu((sum_p avpb[p])@Wl2+bl2)
//     blocks 313..352: CSR bucket fill.  Weights from L2, 1 barrier/block.
// ---------------------------------------------------------------------------
__launch_bounds__(256, 2)
__global__ void k_out(const unsigned short* __restrict__ v_rm,
                      const unsigned short* __restrict__ avpb,
                      const unsigned short* __restrict__ Wl1T, const float* __restrict__ bl1,
                      const unsigned short* __restrict__ Wl2T, const float* __restrict__ bl2,
                      unsigned short* __restrict__ v2b, float* __restrict__ outb,
                      const int* __restrict__ src, const int* __restrict__ dst,
                      int* __restrict__ cursor, int* __restrict__ srcbuf) {
  if (blockIdx.x >= 313) {  // fused bucket fill
    const int e0 = (blockIdx.x - 313) * 256 + threadIdx.x;
    for (int e = e0; e < NEDGE; e += 40 * 256) {
      const int pos = atomicAdd(&cursor[dst[e]], 1);
      srcbuf[pos] = src[e];
    }
    return;
  }
  __shared__ __align__(16) char sm[32768];
  const int t = threadIdx.x, lane = t & 63, wid = t >> 6;
  const int wr = wid & 1, wc = wid >> 1;
  const int r0 = blockIdx.x * 32;

  {
    const int row = t >> 3, grow = r0 + row;
#pragma unroll
    for (int q = 0; q < 4; ++q) {
      const int slot = (t & 7) * 4 + q;
      bf16x8 w = (grow < NN) ? *(const bf16x8*)(v_rm + (size_t)grow * DIMV + slot * 8) : bzero8();
      *(bf16x8*)(sm + row * 512 + ((slot ^ (row & 7)) * 16)) = w;
    }
#pragma unroll
    for (int q = 0; q < 4; ++q) {
      const int slot = (t & 7) * 4 + q;
      float buf[8] = {0.f, 0.f, 0.f, 0.f, 0.f, 0.f, 0.f, 0.f};
      if (grow < NN) {
#pragma unroll
        for (int p = 0; p < SPLIT; ++p) {
          const bf16x8 a =
              *(const bf16x8*)(avpb + (size_t)p * NN * DIMV + (size_t)grow * DIMV + slot * 8);
#pragma unroll
          for (int z = 0; z < 8; ++z) buf[z] += bf2f((unsigned short)a[z]);
        }
      }
      *(bf16x8*)(sm + 16384 + row * 512 + ((slot ^ (row & 7)) * 16)) = pack8(buf);
    }
  }
  __syncthreads();  // single barrier

  f32x4 acc1[8], acc2[8];
#pragma unroll
  for (int i = 0; i < 8; ++i) {
    acc1[i] = (f32x4){0.f, 0.f, 0.f, 0.f};
    acc2[i] = (f32x4){0.f, 0.f, 0.f, 0.f};
  }

#pragma unroll 1
  for (int step = 0; step < 8; ++step) {
    const int arow = 16 * wr + (lane & 15);
    const int aslot = step * 4 + (lane >> 4);
    const bf16x8 a1 = *(const bf16x8*)(sm + arow * 512 + ((aslot ^ (arow & 7)) * 16));
    const bf16x8 a2 = *(const bf16x8*)(sm + 16384 + arow * 512 + ((aslot ^ (arow & 7)) * 16));
    const unsigned short* w1p = Wl1T + step * 8192 + (lane & 15) * 32 + (lane >> 4) * 8;
    const unsigned short* w2p = Wl2T + step * 8192 + (lane & 15) * 32 + (lane >> 4) * 8;
#pragma unroll
    for (int ct = 0; ct < 8; ++ct) {
      const int c0 = 128 * wc + 16 * ct;
      acc1[ct] = __builtin_amdgcn_mfma_f32_16x16x32_bf16(
          a1, *(const bf16x8*)(w1p + c0 * 32), acc1[ct], 0, 0, 0);
      acc2[ct] = __builtin_amdgcn_mfma_f32_16x16x32_bf16(
          a2, *(const bf16x8*)(w2p + c0 * 32), acc2[ct], 0, 0, 0);
    }
  }

  const int growbase = r0 + 16 * wr + (lane >> 4) * 4;
  if (growbase < NN) {
#pragma unroll
    for (int ct = 0; ct < 8; ++ct) {
      const int c = 128 * wc + 16 * ct + (lane & 15);
      const float u1 = bl1[c], u2 = bl2[c];
#pragma unroll
      for (int r = 0; r < 4; ++r) {
        const float x = fmaxf(acc1[ct][r] + u1, 0.f) + fmaxf(acc2[ct][r] + u2, 0.f);
        v2b[(size_t)(growbase + r) * DIMV + c] = f2bf(x);
        outb[(size_t)(growbase + r) * DIMV + c] = x;
      }
    }
  }
}

// ---------------------------------------------------------------------------
// K4: gather-sum from bf16 v2b; one wave per dst node; 8-deep unrolled.
// ---------------------------------------------------------------------------
__launch_bounds__(256)
__global__ void k_gather(const unsigned short* __restrict__ v2b,
                         const int* __restrict__ offsets,
                         const int* __restrict__ srcbuf, float* __restrict__ outb) {
  const int n = (blockIdx.x * 256 + threadIdx.x) >> 6;
  if (n >= NN) return;
  const int lane = threadIdx.x & 63;
  const int beg = offsets[n], end = offsets[n + 1];
  float4 a0 = {0.f, 0.f, 0.f, 0.f}, a1 = a0, a2 = a0, a3 = a0;
  float4 a4 = a0, a5 = a0, a6 = a0, a7 = a0;
  int j = beg;
  for (; j + 8 <= end; j += 8) {
    const int s0 = srcbuf[j], s1 = srcbuf[j + 1], s2 = srcbuf[j + 2], s3 = srcbuf[j + 3];
    const int s4 = srcbuf[j + 4], s5 = srcbuf[j + 5], s6 = srcbuf[j + 6], s7 = srcbuf[j + 7];
    const u16x4 x0 = *(const u16x4*)(v2b + (size_t)s0 * DIMV + lane * 4);
    const u16x4 x1 = *(const u16x4*)(v2b + (size_t)s1 * DIMV + lane * 4);
    const u16x4 x2 = *(const u16x4*)(v2b + (size_t)s2 * DIMV + lane * 4);
    const u16x4 x3 = *(const u16x4*)(v2b + (size_t)s3 * DIMV + lane * 4);
    const u16x4 x4 = *(const u16x4*)(v2b + (size_t)s4 * DIMV + lane * 4);
    const u16x4 x5 = *(const u16x4*)(v2b + (size_t)s5 * DIMV + lane * 4);
    const u16x4 x6 = *(const u16x4*)(v2b + (size_t)s6 * DIMV + lane * 4);
    const u16x4 x7 = *(const u16x4*)(v2b + (size_t)s7 * DIMV + lane * 4);
    a0.x += bf2f(x0[0]); a0.y += bf2f(x0[1]); a0.z += bf2f(x0[2]); a0.w += bf2f(x0[3]);
    a1.x += bf2f(x1[0]); a1.y += bf2f(x1[1]); a1.z += bf2f(x1[2]); a1.w += bf2f(x1[3]);
    a2.x += bf2f(x2[0]); a2.y += bf2f(x2[1]); a2.z += bf2f(x2[2]); a2.w += bf2f(x2[3]);
    a3.x += bf2f(x3[0]); a3.y += bf2f(x3[1]); a3.z += bf2f(x3[2]); a3.w += bf2f(x3[3]);
    a4.x += bf2f(x4[0]); a4.y += bf2f(x4[1]); a4.z += bf2f(x4[2]); a4.w += bf2f(x4[3]);
    a5.x += bf2f(x5[0]); a5.y += bf2f(x5[1]); a5.z += bf2f(x5[2]); a5.w += bf2f(x5[3]);
    a6.x += bf2f(x6[0]); a6.y += bf2f(x6[1]); a6.z += bf2f(x6[2]); a6.w += bf2f(x6[3]);
    a7.x += bf2f(x7[0]); a7.y += bf2f(x7[1]); a7.z += bf2f(x7[2]); a7.w += bf2f(x7[3]);
  }
  for (; j < end; ++j) {
    const int s0 = srcbuf[j];
    const u16x4 x0 = *(const u16x4*)(v2b + (size_t)s0 * DIMV + lane * 4);
    a0.x += bf2f(x0[0]); a0.y += bf2f(x0[1]); a0.z += bf2f(x0[2]); a0.w += bf2f(x0[3]);
  }
  a0.x += a1.x + a2.x + a3.x + a4.x + a5.x + a6.x + a7.x;
  a0.y += a1.y + a2.y + a3.y + a4.y + a5.y + a6.y + a7.y;
  a0.z += a1.z + a2.z + a3.z + a4.z + a5.z + a6.z + a7.z;
  a0.w += a1.w + a2.w + a3.w + a4.w + a5.w + a6.w + a7.w;
  float* o = outb + (size_t)n * DIMV + lane * 4;
  float4 cur = *(const float4*)o;
  cur.x += a0.x; cur.y += a0.y; cur.z += a0.z; cur.w += a0.w;
  *(float4*)o = cur;
}

// ---------------------------------------------------------------------------
extern "C" void kernel_launch(void* const* d_in, const int* in_sizes, int n_in,
                              void* d_out, int out_size, void* d_ws, size_t ws_size,
                              hipStream_t stream) {
  const float* vc  = (const float*)d_in[0];
  const float* A   = (const float*)d_in[1];
  const int*   src = (const int*)d_in[2];
  const int*   dst = (const int*)d_in[3];
  const float* W1  = (const float*)d_in[4];
  const float* b1  = (const float*)d_in[5];
  const float* W2  = (const float*)d_in[6];
  const float* b2  = (const float*)d_in[7];
  const float* Wl1 = (const float*)d_in[8];
  const float* bl1 = (const float*)d_in[9];
  const float* Wl2 = (const float*)d_in[10];
  const float* bl2 = (const float*)d_in[11];
  float* outb = (float*)d_out;
  char* ws = (char*)d_ws;

  // carve (bytes), no aliasing:
  unsigned short* W1T  = (unsigned short*)(ws + 0);
  unsigned short* W2T  = (unsigned short*)(ws + 262144);
  unsigned short* Wl1T = (unsigned short*)(ws + 524288);
  unsigned short* Wl2T = (unsigned short*)(ws + 655360);
  unsigned short* vB   = (unsigned short*)(ws + 786432);     // 313 x 16KB tiles
  unsigned short* v_rm = (unsigned short*)(ws + 5914624);    // [10000][256] bf16
  int* counts  = (int*)(ws + 11034624);
  int* offsets = (int*)(ws + 11075584);
  int* cursor  = (int*)(ws + 11116544);
  int* srcbuf  = (int*)(ws + 11157504);                       // 1.28 MB
  unsigned short* avpb = (unsigned short*)(ws + 12437760);    // SPLIT x [N][256] bf16 (30.7MB)
  unsigned short* v2b  = (unsigned short*)(ws + 43157760);    // [N][256] bf16

  hipLaunchKernelGGL(k_conv, dim3(512), dim3(256), 0, stream,
                     W1, W2, Wl1, Wl2, W1T, W2T, Wl1T, Wl2T, vB, counts);
  hipLaunchKernelGGL(k_mlp, dim3(353), dim3(256), 0, stream,
                     vc, W1T, b1, W2T, b2, v_rm, vB, dst, counts);
  hipLaunchKernelGGL(k_av, dim3(475), dim3(512), 0, stream,
                     A, vB, avpb, counts, offsets, cursor);
  hipLaunchKernelGGL(k_out, dim3(353), dim3(256), 0, stream,
                     v_rm, avpb, Wl1T, bl1, Wl2T, bl2, v2b, outb,
                     src, dst, cursor, srcbuf);
  hipLaunchKernelGGL(k_gather, dim3((NN * 64 + 255) / 256), dim3(256), 0, stream,
                     v2b, offsets, srcbuf, outb);
}

// Round 14
// 227.540 us; speedup vs baseline: 1.0978x; 1.0978x over previous
//
#include <hip/hip_runtime.h>
#include <stdint.h>

#define NN 10000
#define DIMV 256
#define HID 512
#define NEDGE 320000
#define SPLIT 6
#define KCH 1664      // k per chunk (52 tiles); chunk 5: 53 tiles incl. zero-pad tile 312
#define NKT 313
#define APL 2112      // A LDS plane stride bytes (128*16 + 64 pad)
#define ABUF 8448     // 4*APL
#define BOFF 16896    // 2*ABUF
#define LDSZ 49664    // BOFF + 2*16384

typedef __attribute__((ext_vector_type(8))) short bf16x8;
typedef __attribute__((ext_vector_type(4))) float f32x4;
typedef __attribute__((ext_vector_type(4))) unsigned short u16x4;
typedef __attribute__((ext_vector_type(2))) unsigned int u32x2;

__device__ __forceinline__ unsigned short f2bf(float f) {
  union { float f; unsigned int u; } c; c.f = f;
  return (unsigned short)((c.u + 0x7FFFu + ((c.u >> 16) & 1u)) >> 16);
}
__device__ __forceinline__ float bf2f(unsigned short h) {
  union { unsigned int u; float f; } c; c.u = ((unsigned int)h) << 16;
  return c.f;
}

__device__ __forceinline__ bf16x8 bzero8() {
  bf16x8 r;
#pragma unroll
  for (int i = 0; i < 8; ++i) r[i] = 0;
  return r;
}

__device__ __forceinline__ bf16x8 pack8(const float* x) {
  bf16x8 r;
#pragma unroll
  for (int i = 0; i < 8; ++i) r[i] = (short)f2bf(x[i]);
  return r;
}

// f32x4 -> 4 packed bf16 (8B) via v_cvt_pk_bf16_f32 (RNE, matches f2bf)
__device__ __forceinline__ u32x2 cvt4v(const f32x4 a) {
  u32x2 r;
  asm("v_cvt_pk_bf16_f32 %0, %1, %2" : "=v"(r[0]) : "v"(a[0]), "v"(a[1]));
  asm("v_cvt_pk_bf16_f32 %0, %1, %2" : "=v"(r[1]) : "v"(a[2]), "v"(a[3]));
  return r;
}

// async global->LDS, 16B/lane; LDS dest = wave-uniform base + lane*16
typedef __attribute__((address_space(1))) unsigned int gu32;
typedef __attribute__((address_space(3))) unsigned int lu32;
__device__ __forceinline__ void glds16(const void* g, void* l) {
  __builtin_amdgcn_global_load_lds((const gu32*)g, (lu32*)l, 16, 0, 0);
}

// ---------------------------------------------------------------------------
// K0: weights fp32 -> bf16, FRAGMENT-READY [ktile][col][32k] layout (vB-style);
//     zero vB k-pad (tile 312, kk 16..31); zero counts
// ---------------------------------------------------------------------------
__global__ void k_conv(const float* __restrict__ W1, const float* __restrict__ W2,
                       const float* __restrict__ Wl1, const float* __restrict__ Wl2,
                       unsigned short* __restrict__ W1T, unsigned short* __restrict__ W2T,
                       unsigned short* __restrict__ Wl1T, unsigned short* __restrict__ Wl2T,
                       unsigned short* __restrict__ vB, int* __restrict__ counts) {
  int i = blockIdx.x * 256 + threadIdx.x;
  if (i < 131072) {
    {  // W1T fragment-ready: 8 tiles x [512 o][32 kk]; W1 is [256 k][512 o]
      int tile = i >> 14, o = (i >> 5) & 511, kk = i & 31;
      W1T[i] = f2bf(W1[(size_t)(tile * 32 + kk) * 512 + o]);
    }
    {  // W2T fragment-ready: 16 tiles x [256 o][32 kk]; W2 is [512 k][256 o]
      int tile = i >> 13, o = (i >> 5) & 255, kk = i & 31;
      W2T[i] = f2bf(W2[(size_t)(tile * 32 + kk) * 256 + o]);
    }
    if (i < 65536) {  // Wl1/Wl2 fragment-ready: 8 tiles x [256 o][32 kk]
      int tile = i >> 13, o = (i >> 5) & 255, kk = i & 31;
      int srci = (tile * 32 + kk) * 256 + o;
      Wl1T[i] = f2bf(Wl1[srci]);
      Wl2T[i] = f2bf(Wl2[srci]);
    }
    if (i < 4096) {  // zero vB tile 312, kk in [16,32), swizzled address
      int c = i >> 4, kk = 16 + (i & 15);
      int g = kk >> 3;
      int byte = c * 64 + ((g ^ ((c >> 1) & 3)) << 4) + (kk & 7) * 2;
      *(unsigned short*)((char*)vB + (size_t)312 * 16384 + byte) = 0;
    }
    if (i < NN) counts[i] = 0;
  }
}

// ---------------------------------------------------------------------------
// K1: blocks 0..312: v = relu(vc + relu(vc@W1+b1)@W2 + b2) -> v_rm, vB
//     blocks 313..352: dst histogram.  B-operands straight from L2.
// ---------------------------------------------------------------------------
__launch_bounds__(256, 2)
__global__ void k_mlp(const float* __restrict__ vc,
                      const unsigned short* __restrict__ W1T, const float* __restrict__ b1,
                      const unsigned short* __restrict__ W2T, const float* __restrict__ b2,
                      unsigned short* __restrict__ v_rm, unsigned short* __restrict__ vB,
                      const int* __restrict__ dst, int* __restrict__ counts) {
  if (blockIdx.x >= 313) {  // fused histogram
    const int e0 = (blockIdx.x - 313) * 256 + threadIdx.x;
    for (int e = e0; e < NEDGE; e += 40 * 256) atomicAdd(&counts[dst[e]], 1);
    return;
  }
  __shared__ __align__(16) char sm[49152];
  const int t = threadIdx.x;
  const int lane = t & 63, wid = t >> 6;
  const int wr = wid & 1, wc = wid >> 1;
  const int r0 = blockIdx.x * 32;

  {  // stage vc tile -> bf16 (region 0..16K)
    const int row = t >> 3, grow = r0 + row;
#pragma unroll
    for (int q = 0; q < 4; ++q) {
      const int slot = (t & 7) * 4 + q;
      float buf[8] = {0.f, 0.f, 0.f, 0.f, 0.f, 0.f, 0.f, 0.f};
      if (grow < NN) {
        const float4 x0 = *(const float4*)(vc + (size_t)grow * DIMV + slot * 8);
        const float4 x1 = *(const float4*)(vc + (size_t)grow * DIMV + slot * 8 + 4);
        buf[0] = x0.x; buf[1] = x0.y; buf[2] = x0.z; buf[3] = x0.w;
        buf[4] = x1.x; buf[5] = x1.y; buf[6] = x1.z; buf[7] = x1.w;
      }
      *(bf16x8*)(sm + row * 512 + ((slot ^ (row & 7)) * 16)) = pack8(buf);
    }
  }
  __syncthreads();  // barrier #1: vcb ready

  f32x4 acc1[16];
#pragma unroll
  for (int i = 0; i < 16; ++i) acc1[i] = (f32x4){0.f, 0.f, 0.f, 0.f};

#pragma unroll 1
  for (int step = 0; step < 8; ++step) {
    const int arow = 16 * wr + (lane & 15);
    const int aslot = step * 4 + (lane >> 4);
    const bf16x8 af = *(const bf16x8*)(sm + arow * 512 + ((aslot ^ (arow & 7)) * 16));
    const unsigned short* wb = W1T + step * 16384 + (lane & 15) * 32 + (lane >> 4) * 8;
#pragma unroll
    for (int ct = 0; ct < 16; ++ct) {
      const int c0 = 256 * wc + 16 * ct;
      const bf16x8 bfr = *(const bf16x8*)(wb + c0 * 32);
      acc1[ct] = __builtin_amdgcn_mfma_f32_16x16x32_bf16(af, bfr, acc1[ct], 0, 0, 0);
    }
  }

  // h = relu(acc1 + b1) -> bf16 LDS [32][512] at 16384 (vcb dead)
#pragma unroll
  for (int ct = 0; ct < 16; ++ct) {
    const int c = 256 * wc + 16 * ct + (lane & 15);
    const float bb = b1[c];
#pragma unroll
    for (int r = 0; r < 4; ++r) {
      const int row = 16 * wr + (lane >> 4) * 4 + r;
      float v = fmaxf(acc1[ct][r] + bb, 0.f);
      const int slot = c >> 3;
      *(unsigned short*)(sm + 16384 + row * 1024 + ((slot ^ (row & 7)) * 16) + (c & 7) * 2) =
          f2bf(v);
    }
  }
  __syncthreads();  // barrier #2: h ready

  f32x4 acc2[8];
#pragma unroll
  for (int i = 0; i < 8; ++i) acc2[i] = (f32x4){0.f, 0.f, 0.f, 0.f};

#pragma unroll 1
  for (int step = 0; step < 16; ++step) {
    const int arow = 16 * wr + (lane & 15);
    const int aslot = step * 4 + (lane >> 4);
    const bf16x8 af = *(const bf16x8*)(sm + 16384 + arow * 1024 + ((aslot ^ (arow & 7)) * 16));
    const unsigned short* wb = W2T + step * 8192 + (lane & 15) * 32 + (lane >> 4) * 8;
#pragma unroll
    for (int ct = 0; ct < 8; ++ct) {
      const int c0 = 128 * wc + 16 * ct;
      const bf16x8 bfr = *(const bf16x8*)(wb + c0 * 32);
      acc2[ct] = __builtin_amdgcn_mfma_f32_16x16x32_bf16(af, bfr, acc2[ct], 0, 0, 0);
    }
  }

  const int growbase = r0 + 16 * wr + (lane >> 4) * 4;
  if (growbase < NN) {
#pragma unroll
    for (int ct = 0; ct < 8; ++ct) {
      const int c = 128 * wc + 16 * ct + (lane & 15);
      const float bb = b2[c];
      u16x4 pk;
#pragma unroll
      for (int r = 0; r < 4; ++r) {
        const int grow = growbase + r;
        float v = acc2[ct][r] + bb + vc[(size_t)grow * DIMV + c];
        v = fmaxf(v, 0.f);
        const unsigned short hv = f2bf(v);
        v_rm[(size_t)grow * DIMV + c] = hv;
        pk[r] = hv;
      }
      const int tile = growbase >> 5, kk0 = growbase & 31;
      const int g = kk0 >> 3;
      const int byte = c * 64 + ((g ^ ((c >> 1) & 3)) << 4) + (kk0 & 7) * 2;
      *(u16x4*)((char*)vB + (size_t)tile * 16384 + byte) = pk;
    }
  }
}

// ---------------------------------------------------------------------------
// K2: blocks 0..473: Av = A @ v (R8/R12-proven: BM=128, BN=256, BK=32, A regs->
// LDS dbuf, B glds dbuf, 1 barrier/step). block 474: fused exclusive scan.
// ---------------------------------------------------------------------------
__launch_bounds__(512, 4)
__global__ void k_av(const float* __restrict__ A, const unsigned short* __restrict__ vB,
                     unsigned short* __restrict__ avpb,
                     const int* __restrict__ counts, int* __restrict__ offsets,
                     int* __restrict__ cursor) {
  __shared__ __align__(16) char sm[LDSZ];
  const int t = threadIdx.x, lane = t & 63, wid = t >> 6;

  if (blockIdx.x >= 474) {  // fused exclusive scan (512 threads, 8 waves)
    int* wred = (int*)sm;
    int carry = 0;
    for (int base = 0; base < NN; base += 512) {
      const int i = base + t;
      const int x = (i < NN) ? counts[i] : 0;
      int v = x;
#pragma unroll
      for (int d = 1; d < 64; d <<= 1) {
        int y = __shfl_up(v, d);
        if (lane >= d) v += y;
      }
      if (lane == 63) wred[wid] = v;
      __syncthreads();
      if (t < 8) {
        int sv = wred[t];
#pragma unroll
        for (int d = 1; d < 8; d <<= 1) {
          int y = __shfl_up(sv, d);
          if (t >= d) sv += y;
        }
        wred[t] = sv;
      }
      __syncthreads();
      const int excl = carry + (wid ? wred[wid - 1] : 0) + v - x;
      if (i < NN) { offsets[i] = excl; cursor[i] = excl; }
      carry += wred[7];
      __syncthreads();
    }
    if (t == 0) offsets[NN] = carry;
    return;
  }

  const int wr = wid >> 2, wc = wid & 3;

  // bijective XCD-chunked remap of 474 blocks
  const int orig = blockIdx.x;
  const int xcd = orig & 7, idx = orig >> 3;
  const int g = (xcd < 2) ? xcd * 60 + idx : 120 + (xcd - 2) * 59 + idx;
  const int s = g / 79;          // k-chunk 0..5
  const int xb = g - s * 79;     // row-block 0..78
  const int r0 = xb * 128;
  const int kbase = s * KCH;
  const int tile0 = s * 52;
  const int nst = (s == SPLIT - 1) ? 53 : 52;
  unsigned short* outp = avpb + (size_t)s * NN * DIMV;

  const int srow = t >> 3, sQ = t & 7;
  const float* ap0 = A + (size_t)min(r0 + srow, NN - 1) * NN;
  const float* ap1 = A + (size_t)min(r0 + 64 + srow, NN - 1) * NN;
  const int wbase = (sQ >> 1) * APL + (sQ & 1) * 8;
  const int w0 = wbase + srow * 16;
  const int w1 = wbase + (64 + srow) * 16;

  f32x4 aR0, aR1;

#define AISSUE(ST)                                            \
  do {                                                        \
    int kq = min(kbase + (ST)*32 + sQ * 4, 9996);             \
    aR0 = *(const f32x4*)(ap0 + kq);                          \
    aR1 = *(const f32x4*)(ap1 + kq);                          \
  } while (0)

#define AWRITE(BUF)                                           \
  do {                                                        \
    char* wb = sm + (BUF)*ABUF;                               \
    *(u32x2*)(wb + w0) = cvt4v(aR0);                          \
    *(u32x2*)(wb + w1) = cvt4v(aR1);                          \
  } while (0)

#define BSTAGE(BUF, TILE)                                                     \
  do {                                                                        \
    char* lb = sm + BOFF + (BUF)*16384 + wid * 1024;                          \
    const char* gp = (const char*)vB + (size_t)(TILE)*16384 + wid * 1024 +    \
                     lane * 16;                                               \
    glds16(gp, lb);                                                           \
    glds16(gp + 8192, lb + 8192);                                             \
  } while (0)

  f32x4 acc[4][4];
#pragma unroll
  for (int i = 0; i < 4; ++i)
#pragma unroll
    for (int j = 0; j < 4; ++j) acc[i][j] = (f32x4){0.f, 0.f, 0.f, 0.f};

  const int rbase = (lane >> 4) * APL + (wr * 64 + (lane & 15)) * 16;
  int boff[4];
#pragma unroll
  for (int ct = 0; ct < 4; ++ct) {
    const int col = wc * 64 + ct * 16 + (lane & 15);
    boff[ct] = col * 64 + (((lane >> 4) ^ ((col >> 1) & 3)) << 4);
  }

#define COMPUTE(CUR)                                                               \
  do {                                                                            \
    const char* ab = sm + (CUR)*ABUF;                                             \
    const char* bb = sm + BOFF + (CUR)*16384;                                     \
    const bf16x8 af0 = *(const bf16x8*)(ab + rbase);                              \
    const bf16x8 af1 = *(const bf16x8*)(ab + rbase + 256);                        \
    const bf16x8 af2 = *(const bf16x8*)(ab + rbase + 512);                        \
    const bf16x8 af3 = *(const bf16x8*)(ab + rbase + 768);                        \
    _Pragma("unroll") for (int ct = 0; ct < 4; ++ct) {                            \
      const bf16x8 bfr = *(const bf16x8*)(bb + boff[ct]);                         \
      acc[0][ct] = __builtin_amdgcn_mfma_f32_16x16x32_bf16(af0, bfr, acc[0][ct], 0, 0, 0); \
      acc[1][ct] = __builtin_amdgcn_mfma_f32_16x16x32_bf16(af1, bfr, acc[1][ct], 0, 0, 0); \
      acc[2][ct] = __builtin_amdgcn_mfma_f32_16x16x32_bf16(af2, bfr, acc[2][ct], 0, 0, 0); \
      acc[3][ct] = __builtin_amdgcn_mfma_f32_16x16x32_bf16(af3, bfr, acc[3][ct], 0, 0, 0); \
    }                                                                             \
  } while (0)

  // prologue
  AISSUE(0);
  AWRITE(0);
  BSTAGE(0, tile0);
  __syncthreads();

  int cur = 0;
  for (int st = 0; st < nst; ++st) {
    const bool more = (st + 1 < nst);
    if (more) {
      AISSUE(st + 1);                  // A HBM loads first (long pole)
      BSTAGE(cur ^ 1, tile0 + st + 1); // then B glds (L2)
    }
    COMPUTE(cur);
    if (more) AWRITE(cur ^ 1);         // cvt+ds_write after MFMA cluster
    __syncthreads();
    cur ^= 1;
  }
#undef AISSUE
#undef AWRITE
#undef BSTAGE
#undef COMPUTE

  // epilogue: bf16 partials
#pragma unroll
  for (int rt = 0; rt < 4; ++rt) {
    const int gb = r0 + wr * 64 + rt * 16 + (lane >> 4) * 4;
    if (gb < NN) {
#pragma unroll
      for (int ct = 0; ct < 4; ++ct) {
        const int col = wc * 64 + ct * 16 + (lane & 15);
#pragma unroll
        for (int r = 0; r < 4; ++r)
          outp[(size_t)(gb + r) * DIMV + col] = f2bf(acc[rt][ct][r]);
      }
    }
  }
}

// ---------------------------------------------------------------------------
// K3: blocks 0..312: v2 = relu(v@Wl1+bl1) + relu((sum_p avpb[p])@Wl2+bl2)
//     -> v2b ONLY (k_gather is the sole d_out writer).
//     blocks 313..352: CSR bucket fill.
// ---------------------------------------------------------------------------
__launch_bounds__(256, 2)
__global__ void k_out(const unsigned short* __restrict__ v_rm,
                      const unsigned short* __restrict__ avpb,
                      const unsigned short* __restrict__ Wl1T, const float* __restrict__ bl1,
                      const unsigned short* __restrict__ Wl2T, const float* __restrict__ bl2,
                      unsigned short* __restrict__ v2b,
                      const int* __restrict__ src, const int* __restrict__ dst,
                      int* __restrict__ cursor, int* __restrict__ srcbuf) {
  if (blockIdx.x >= 313) {  // fused bucket fill
    const int e0 = (blockIdx.x - 313) * 256 + threadIdx.x;
    for (int e = e0; e < NEDGE; e += 40 * 256) {
      const int pos = atomicAdd(&cursor[dst[e]], 1);
      srcbuf[pos] = src[e];
    }
    return;
  }
  __shared__ __align__(16) char sm[32768];
  const int t = threadIdx.x, lane = t & 63, wid = t >> 6;
  const int wr = wid & 1, wc = wid >> 1;
  const int r0 = blockIdx.x * 32;

  {
    const int row = t >> 3, grow = r0 + row;
#pragma unroll
    for (int q = 0; q < 4; ++q) {
      const int slot = (t & 7) * 4 + q;
      bf16x8 w = (grow < NN) ? *(const bf16x8*)(v_rm + (size_t)grow * DIMV + slot * 8) : bzero8();
      *(bf16x8*)(sm + row * 512 + ((slot ^ (row & 7)) * 16)) = w;
    }
#pragma unroll
    for (int q = 0; q < 4; ++q) {
      const int slot = (t & 7) * 4 + q;
      float buf[8] = {0.f, 0.f, 0.f, 0.f, 0.f, 0.f, 0.f, 0.f};
      if (grow < NN) {
#pragma unroll
        for (int p = 0; p < SPLIT; ++p) {
          const bf16x8 a =
              *(const bf16x8*)(avpb + (size_t)p * NN * DIMV + (size_t)grow * DIMV + slot * 8);
#pragma unroll
          for (int z = 0; z < 8; ++z) buf[z] += bf2f((unsigned short)a[z]);
        }
      }
      *(bf16x8*)(sm + 16384 + row * 512 + ((slot ^ (row & 7)) * 16)) = pack8(buf);
    }
  }
  __syncthreads();  // single barrier

  f32x4 acc1[8], acc2[8];
#pragma unroll
  for (int i = 0; i < 8; ++i) {
    acc1[i] = (f32x4){0.f, 0.f, 0.f, 0.f};
    acc2[i] = (f32x4){0.f, 0.f, 0.f, 0.f};
  }

#pragma unroll 1
  for (int step = 0; step < 8; ++step) {
    const int arow = 16 * wr + (lane & 15);
    const int aslot = step * 4 + (lane >> 4);
    const bf16x8 a1 = *(const bf16x8*)(sm + arow * 512 + ((aslot ^ (arow & 7)) * 16));
    const bf16x8 a2 = *(const bf16x8*)(sm + 16384 + arow * 512 + ((aslot ^ (arow & 7)) * 16));
    const unsigned short* w1p = Wl1T + step * 8192 + (lane & 15) * 32 + (lane >> 4) * 8;
    const unsigned short* w2p = Wl2T + step * 8192 + (lane & 15) * 32 + (lane >> 4) * 8;
#pragma unroll
    for (int ct = 0; ct < 8; ++ct) {
      const int c0 = 128 * wc + 16 * ct;
      acc1[ct] = __builtin_amdgcn_mfma_f32_16x16x32_bf16(
          a1, *(const bf16x8*)(w1p + c0 * 32), acc1[ct], 0, 0, 0);
      acc2[ct] = __builtin_amdgcn_mfma_f32_16x16x32_bf16(
          a2, *(const bf16x8*)(w2p + c0 * 32), acc2[ct], 0, 0, 0);
    }
  }

  const int growbase = r0 + 16 * wr + (lane >> 4) * 4;
  if (growbase < NN) {
#pragma unroll
    for (int ct = 0; ct < 8; ++ct) {
      const int c = 128 * wc + 16 * ct + (lane & 15);
      const float u1 = bl1[c], u2 = bl2[c];
#pragma unroll
      for (int r = 0; r < 4; ++r) {
        const float x = fmaxf(acc1[ct][r] + u1, 0.f) + fmaxf(acc2[ct][r] + u2, 0.f);
        v2b[(size_t)(growbase + r) * DIMV + c] = f2bf(x);
      }
    }
  }
}

// ---------------------------------------------------------------------------
// K4: gather-sum. TWO nodes per wave (32 lanes x 16B each), 8-deep unrolled.
// Writes d_out exactly once: out[n] = v2b[n] + sum_{s in bucket(n)} v2b[s].
// ---------------------------------------------------------------------------
__launch_bounds__(256)
__global__ void k_gather(const unsigned short* __restrict__ v2b,
                         const int* __restrict__ offsets,
                         const int* __restrict__ srcbuf, float* __restrict__ outb) {
  const int w = (blockIdx.x * 256 + threadIdx.x) >> 6;  // global wave id
  const int lane = threadIdx.x & 63;
  const int half = lane >> 5, hl = lane & 31;
  const int n = 2 * w + half;
  if (n >= NN) return;
  const int beg = offsets[n], end = offsets[n + 1];

  float acc[8];
  {  // own row: out = v2 + gather
    const bf16x8 x = *(const bf16x8*)(v2b + (size_t)n * DIMV + hl * 8);
#pragma unroll
    for (int k = 0; k < 8; ++k) acc[k] = bf2f((unsigned short)x[k]);
  }

  int j = beg;
  for (; j + 8 <= end; j += 8) {
    const int s0 = srcbuf[j], s1 = srcbuf[j + 1], s2 = srcbuf[j + 2], s3 = srcbuf[j + 3];
    const int s4 = srcbuf[j + 4], s5 = srcbuf[j + 5], s6 = srcbuf[j + 6], s7 = srcbuf[j + 7];
    const bf16x8 x0 = *(const bf16x8*)(v2b + (size_t)s0 * DIMV + hl * 8);
    const bf16x8 x1 = *(const bf16x8*)(v2b + (size_t)s1 * DIMV + hl * 8);
    const bf16x8 x2 = *(const bf16x8*)(v2b + (size_t)s2 * DIMV + hl * 8);
    const bf16x8 x3 = *(const bf16x8*)(v2b + (size_t)s3 * DIMV + hl * 8);
    const bf16x8 x4 = *(const bf16x8*)(v2b + (size_t)s4 * DIMV + hl * 8);
    const bf16x8 x5 = *(const bf16x8*)(v2b + (size_t)s5 * DIMV + hl * 8);
    const bf16x8 x6 = *(const bf16x8*)(v2b + (size_t)s6 * DIMV + hl * 8);
    const bf16x8 x7 = *(const bf16x8*)(v2b + (size_t)s7 * DIMV + hl * 8);
#pragma unroll
    for (int k = 0; k < 8; ++k) {
      acc[k] += bf2f((unsigned short)x0[k]) + bf2f((unsigned short)x1[k]) +
                bf2f((unsigned short)x2[k]) + bf2f((unsigned short)x3[k]) +
                bf2f((unsigned short)x4[k]) + bf2f((unsigned short)x5[k]) +
                bf2f((unsigned short)x6[k]) + bf2f((unsigned short)x7[k]);
    }
  }
  for (; j < end; ++j) {
    const int s0 = srcbuf[j];
    const bf16x8 x0 = *(const bf16x8*)(v2b + (size_t)s0 * DIMV + hl * 8);
#pragma unroll
    for (int k = 0; k < 8; ++k) acc[k] += bf2f((unsigned short)x0[k]);
  }

  float* o = outb + (size_t)n * DIMV + hl * 8;
  float4 lo = {acc[0], acc[1], acc[2], acc[3]};
  float4 hi = {acc[4], acc[5], acc[6], acc[7]};
  *(float4*)o = lo;
  *(float4*)(o + 4) = hi;
}

// ---------------------------------------------------------------------------
extern "C" void kernel_launch(void* const* d_in, const int* in_sizes, int n_in,
                              void* d_out, int out_size, void* d_ws, size_t ws_size,
                              hipStream_t stream) {
  const float* vc  = (const float*)d_in[0];
  const float* A   = (const float*)d_in[1];
  const int*   src = (const int*)d_in[2];
  const int*   dst = (const int*)d_in[3];
  const float* W1  = (const float*)d_in[4];
  const float* b1  = (const float*)d_in[5];
  const float* W2  = (const float*)d_in[6];
  const float* b2  = (const float*)d_in[7];
  const float* Wl1 = (const float*)d_in[8];
  const float* bl1 = (const float*)d_in[9];
  const float* Wl2 = (const float*)d_in[10];
  const float* bl2 = (const float*)d_in[11];
  float* outb = (float*)d_out;
  char* ws = (char*)d_ws;

  // carve (bytes), no aliasing:
  unsigned short* W1T  = (unsigned short*)(ws + 0);
  unsigned short* W2T  = (unsigned short*)(ws + 262144);
  unsigned short* Wl1T = (unsigned short*)(ws + 524288);
  unsigned short* Wl2T = (unsigned short*)(ws + 655360);
  unsigned short* vB   = (unsigned short*)(ws + 786432);     // 313 x 16KB tiles
  unsigned short* v_rm = (unsigned short*)(ws + 5914624);    // [10000][256] bf16
  int* counts  = (int*)(ws + 11034624);
  int* offsets = (int*)(ws + 11075584);
  int* cursor  = (int*)(ws + 11116544);
  int* srcbuf  = (int*)(ws + 11157504);                       // 1.28 MB
  unsigned short* avpb = (unsigned short*)(ws + 12437760);    // SPLIT x [N][256] bf16 (30.7MB)
  unsigned short* v2b  = (unsigned short*)(ws + 43157760);    // [N][256] bf16

  hipLaunchKernelGGL(k_conv, dim3(512), dim3(256), 0, stream,
                     W1, W2, Wl1, Wl2, W1T, W2T, Wl1T, Wl2T, vB, counts);
  hipLaunchKernelGGL(k_mlp, dim3(353), dim3(256), 0, stream,
                     vc, W1T, b1, W2T, b2, v_rm, vB, dst, counts);
  hipLaunchKernelGGL(k_av, dim3(475), dim3(512), 0, stream,
                     A, vB, avpb, counts, offsets, cursor);
  hipLaunchKernelGGL(k_out, dim3(353), dim3(256), 0, stream,
                     v_rm, avpb, Wl1T, bl1, Wl2T, bl2, v2b,
                     src, dst, cursor, srcbuf);
  hipLaunchKernelGGL(k_gather, dim3(1250), dim3(256), 0, stream,
                     v2b, offsets, srcbuf, outb);
}